// Round 10
// baseline (148.794 us; speedup 1.0000x reference)
//
#include <hip/hip_runtime.h>

// ============================================================================
// ROUND 10 = DIAGNOSTIC ROUND. Each wave runs the full pipeline TWICE
// (batch b, then batch b^4096), so every out[i] is written twice with
// bit-identical values (idempotent, race-safe). This doubles kernel time to
// ~52us, lifting it back into the rocprof top-5 window (cutoff ~41us fills)
// so we finally get FETCH/WRITE/conflict/VALU counters for the 26us plateau
// that rounds 7/8/9 (streaming, waitcnt, occupancy) all failed to move.
// ============================================================================

#define WIRE_DIM  32
#define NUM_WIRES 64
#define BATCH     8192
#define HID       10
#define STRIDE    36   // 32 + 4 pad: conflict-free b128 stage writes/reads

// broadcast-read a float from a wave-uniform lane index -> scalar
__device__ __forceinline__ float rl(float x, int slane) {
    return __uint_as_float(__builtin_amdgcn_readlane(__float_as_uint(x), slane));
}

__global__ __launch_bounds__(256) void isnet_kernel(
    const float* __restrict__ outputs,
    const int*   __restrict__ tests,
    const float* __restrict__ W1,
    const float* __restrict__ bias1,
    const float* __restrict__ W2,
    const float* __restrict__ bias2,
    float*       __restrict__ out)
{
    // wave-private staging: 4 waves x 64 rows x 36 floats = 36 KB/block
    __shared__ __align__(16) float stage[4][NUM_WIRES * STRIDE];

    const int tid  = threadIdx.x;
    const int lane = tid & 63;
    const int wave = tid >> 6;
    float* buf = stage[wave];

    const int w0 = blockIdx.x * 4 + wave;        // wave id 0..8191
    const int r  = lane >> 3;                    // LDS row-group within slab
    const int cc = lane & 7;                     // 16B chunk within row

    #pragma unroll 1
    for (int pass = 0; pass < 2; ++pass) {
        const int b = w0 ^ (pass << 12);         // pass 0: b=w0, pass 1: b=w0^4096

        const int sp = __builtin_amdgcn_readfirstlane(tests[2 * b]);      // person
        const int sl = __builtin_amdgcn_readfirstlane(tests[2 * b + 1]);  // location

        // ---- stage coalesced: 8 x contiguous-1KB wave loads -> padded LDS ----
        const float* g = outputs + (size_t)b * (NUM_WIRES * WIRE_DIM) + lane * 4;
        {
            float4 c[8];
            #pragma unroll
            for (int t = 0; t < 8; ++t) c[t] = *(const float4*)(g + t * 256);
            #pragma unroll
            for (int t = 0; t < 8; ++t)
                *(float4*)&buf[(t * 8 + r) * STRIDE + cc * 4] = c[t];
        }
        // wave-private buffer: no __syncthreads needed

        // ---- readback once into registers: own wire row + person row ----
        float4 x[8], p[8];
        #pragma unroll
        for (int t = 0; t < 8; ++t)
            x[t] = *(const float4*)&buf[lane * STRIDE + t * 4];
        #pragma unroll
        for (int t = 0; t < 8; ++t)              // uniform addr -> broadcast
            p[t] = *(const float4*)&buf[sp * STRIDE + t * 4];

        float acc[HID];
        #pragma unroll
        for (int h = 0; h < HID; ++h) acc[h] = bias1[h];   // uniform -> s_load

        // pure-FMA unrolled body (R8 structure, best understood)
        #pragma unroll
        for (int j = 0; j < 8; ++j) {
            const float* wp = W1 + (4 * j) * HID;        // person rows 4j..4j+3
            const float* ww = W1 + (32 + 4 * j) * HID;   // wire rows 32+4j..
            #pragma unroll
            for (int h = 0; h < HID; ++h) {
                acc[h] += p[j].x * wp[0 * HID + h] + p[j].y * wp[1 * HID + h]
                        + p[j].z * wp[2 * HID + h] + p[j].w * wp[3 * HID + h]
                        + x[j].x * ww[0 * HID + h] + x[j].y * ww[1 * HID + h]
                        + x[j].z * ww[2 * HID + h] + x[j].w * ww[3 * HID + h];
            }
        }

        // ---- relu -> W2 -> logit per lane(=wire) -> wave softmax -> loss ----
        float v = bias2[0];
        #pragma unroll
        for (int h = 0; h < HID; ++h) v += fmaxf(acc[h], 0.f) * W2[h];

        float m = v;
        #pragma unroll
        for (int off = 32; off > 0; off >>= 1) m = fmaxf(m, __shfl_xor(m, off));
        float s = __expf(v - m);
        #pragma unroll
        for (int off = 32; off > 0; off >>= 1) s += __shfl_xor(s, off);
        float lv = rl(v, sl);                        // logit at `location`
        if (lane == 0) out[b] = m + __logf(s) - lv;  // -log_softmax[loc]
    }
}

extern "C" void kernel_launch(void* const* d_in, const int* in_sizes, int n_in,
                              void* d_out, int out_size, void* d_ws, size_t ws_size,
                              hipStream_t stream) {
    const float* outputs = (const float*)d_in[0];
    const int*   tests   = (const int*)d_in[1];
    const float* W1      = (const float*)d_in[2];
    const float* b1      = (const float*)d_in[3];
    const float* W2      = (const float*)d_in[4];
    const float* b2      = (const float*)d_in[5];
    float* out = (float*)d_out;

    // 2048 blocks x 4 waves; each wave does batches {w0, w0^4096} -> every
    // output written twice, bit-identically (diagnostic 2x work)
    isnet_kernel<<<BATCH / 4, 256, 0, stream>>>(
        outputs, tests, W1, b1, W2, b2, out);
}

// Round 11
// 101.525 us; speedup vs baseline: 1.4656x; 1.4656x over previous
//
#include <hip/hip_runtime.h>

#define WIRE_DIM  32
#define NUM_WIRES 64
#define BATCH     8192
#define HID       10
#define STRIDE    36   // 32 + 4 pad: conflict-free b128 stage writes/reads

// broadcast-read a float from a wave-uniform lane index -> scalar
__device__ __forceinline__ float rl(float x, int slane) {
    return __uint_as_float(__builtin_amdgcn_readlane(__float_as_uint(x), slane));
}

__global__ __launch_bounds__(256) void isnet_kernel(
    const float* __restrict__ outputs,
    const int*   __restrict__ tests,
    const float* __restrict__ W1,
    const float* __restrict__ bias1,
    const float* __restrict__ W2,
    const float* __restrict__ bias2,
    float*       __restrict__ out)
{
    // wave-private staging: 4 waves x 64 rows x 36 floats = 36 KB/block
    __shared__ __align__(16) float stage[4][NUM_WIRES * STRIDE];

    const int tid  = threadIdx.x;
    const int lane = tid & 63;
    const int wave = tid >> 6;
    float* buf = stage[wave];

    const int b = blockIdx.x * 4 + wave;          // one batch per wave

    const int sp = __builtin_amdgcn_readfirstlane(tests[2 * b]);      // person
    const int sl = __builtin_amdgcn_readfirstlane(tests[2 * b + 1]);  // location

    // ---- person-half weights: loaded ONCE per kernel, lane-distributed ----
    // R10 diagnostic: compute-bound (VALUBusy 67%, HBM 11%, 2x-compute => 2x
    // time). The person half of x.W1 is identical across all 64 lanes ->
    // compute it cooperatively. lane l owns d=l&31, h-group h0=5*(l>>5).
    const int d  = lane & 31;
    const int h0 = (lane >> 5) * 5;
    float wp5[5];
    #pragma unroll
    for (int k = 0; k < 5; ++k) wp5[k] = W1[d * HID + h0 + k];

    // ---- stage coalesced: 8 x contiguous-1KB wave loads -> padded LDS ----
    const float* g = outputs + (size_t)b * (NUM_WIRES * WIRE_DIM) + lane * 4;
    const int r  = lane >> 3;                     // row-group within slab
    const int cc = lane & 7;                      // 16B chunk within row
    {
        float4 c[8];
        #pragma unroll
        for (int t = 0; t < 8; ++t) c[t] = *(const float4*)(g + t * 256);
        #pragma unroll
        for (int t = 0; t < 8; ++t)
            *(float4*)&buf[(t * 8 + r) * STRIDE + cc * 4] = c[t];
    }
    // wave-private buffer: no __syncthreads needed

    // ---- cooperative person projection: pacc[h] = sum_d person[d]*W1[d][h].
    // 1 ds_read (broadcast pair) + 5 FMA + 25 shuffle/add + 10 readlane,
    // replacing 320 redundant per-lane FMAs + 8 ds_read_b128 + 320 weight dwords
    float pc[5];
    {
        const float pd = buf[sp * STRIDE + d];    // lanes l, l+32 same addr
        #pragma unroll
        for (int k = 0; k < 5; ++k) pc[k] = pd * wp5[k];
        #pragma unroll
        for (int off = 16; off > 0; off >>= 1)
            #pragma unroll
            for (int k = 0; k < 5; ++k) pc[k] += __shfl_xor(pc[k], off);
    }
    // half 0 lanes hold pacc[0..4], half 1 lanes hold pacc[5..9] -> SGPRs
    float pacc[HID];
    #pragma unroll
    for (int k = 0; k < 5; ++k) {
        pacc[k]     = rl(pc[k], 0);
        pacc[5 + k] = rl(pc[k], 32);
    }

    // ---- own wire row -> registers (8 x ds_read_b128, conflict-free) ----
    float4 x[8];
    #pragma unroll
    for (int t = 0; t < 8; ++t)
        x[t] = *(const float4*)&buf[lane * STRIDE + t * 4];

    float acc[HID];
    #pragma unroll
    for (int h = 0; h < HID; ++h) acc[h] = bias1[h] + pacc[h];

    // ---- wire half only: 320 FMAs, weights uniform -> s_load ----
    #pragma unroll
    for (int j = 0; j < 8; ++j) {
        const float* ww = W1 + (32 + 4 * j) * HID;   // wire rows 32+4j..
        #pragma unroll
        for (int h = 0; h < HID; ++h) {
            acc[h] += x[j].x * ww[0 * HID + h] + x[j].y * ww[1 * HID + h]
                    + x[j].z * ww[2 * HID + h] + x[j].w * ww[3 * HID + h];
        }
    }

    // ---- relu -> W2 -> logit per lane(=wire) -> wave softmax -> loss ----
    float v = bias2[0];
    #pragma unroll
    for (int h = 0; h < HID; ++h) v += fmaxf(acc[h], 0.f) * W2[h];

    float m = v;
    #pragma unroll
    for (int off = 32; off > 0; off >>= 1) m = fmaxf(m, __shfl_xor(m, off));
    float s = __expf(v - m);
    #pragma unroll
    for (int off = 32; off > 0; off >>= 1) s += __shfl_xor(s, off);
    float lv = rl(v, sl);                        // logit at `location`
    if (lane == 0) out[b] = m + __logf(s) - lv;  // -log_softmax[loc]
}

extern "C" void kernel_launch(void* const* d_in, const int* in_sizes, int n_in,
                              void* d_out, int out_size, void* d_ws, size_t ws_size,
                              hipStream_t stream) {
    const float* outputs = (const float*)d_in[0];
    const int*   tests   = (const int*)d_in[1];
    const float* W1      = (const float*)d_in[2];
    const float* b1      = (const float*)d_in[3];
    const float* W2      = (const float*)d_in[4];
    const float* b2      = (const float*)d_in[5];
    float* out = (float*)d_out;

    // 4 batches per block (4 waves x 1 batch) -> 2048 blocks
    isnet_kernel<<<BATCH / 4, 256, 0, stream>>>(
        outputs, tests, W1, b1, W2, b2, out);
}